// Round 1
// baseline (350.818 us; speedup 1.0000x reference)
//
#include <hip/hip_runtime.h>

#define N_POINTS 16384
#define D_FEAT   256
#define K_NB     8

// ---------------- Kernel A: rnorm[i] = 1 / max(||feat[i]||, 1e-12) ----------
__global__ __launch_bounds__(256) void norms_kernel(const float* __restrict__ feat,
                                                    float* __restrict__ rnorm) {
    const int wave = threadIdx.x >> 6;
    const int lane = threadIdx.x & 63;
    const int row  = blockIdx.x * 4 + wave;
    if (row >= N_POINTS) return;
    const float4* f4 = reinterpret_cast<const float4*>(feat + (size_t)row * D_FEAT);
    float4 v = f4[lane];                       // 64 lanes x 4 = 256 elems
    float s = v.x * v.x + v.y * v.y + v.z * v.z + v.w * v.w;
    #pragma unroll
    for (int off = 32; off > 0; off >>= 1) s += __shfl_xor(s, off, 64);
    if (lane == 0) rnorm[row] = 1.0f / fmaxf(sqrtf(s), 1e-12f);
}

// ---------------- Kernel B: per-point 8-NN + cosine partial -----------------
__device__ __forceinline__ unsigned long long pack_key(float d, int j) {
    // d >= 0 -> float bits are monotonic as uint; j unique per candidate
    return ((unsigned long long)__float_as_uint(d) << 32) | (unsigned int)j;
}

__global__ __launch_bounds__(256) void knn_cos_kernel(const float* __restrict__ coords,
                                                      const float* __restrict__ feat,
                                                      const float* __restrict__ rnorm,
                                                      float* __restrict__ partial) {
    const int i    = blockIdx.x;
    const int tid  = threadIdx.x;
    const int lane = tid & 63;
    const int wave = tid >> 6;

    const float xi = coords[3 * i + 0];
    const float yi = coords[3 * i + 1];
    const float zi = coords[3 * i + 2];

    // ---- per-thread top-8 (sorted ascending), static indexing only ----
    float bd[8];
    int   bi[8];
    #pragma unroll
    for (int k = 0; k < 8; ++k) { bd[k] = 3.4e38f; bi[k] = -1; }

    for (int j = tid; j < N_POINTS; j += 256) {
        const float dx = coords[3 * j + 0] - xi;
        const float dy = coords[3 * j + 1] - yi;
        const float dz = coords[3 * j + 2] - zi;
        const float d2 = fmaf(dx, dx, fmaf(dy, dy, dz * dz));
        if (j == i) continue;                  // exclude self (== ref drop col 0)
        if (d2 < bd[7]) {
            bd[7] = d2; bi[7] = j;
            #pragma unroll
            for (int k = 7; k > 0; --k) {
                if (bd[k] < bd[k - 1]) {
                    float td = bd[k]; bd[k] = bd[k - 1]; bd[k - 1] = td;
                    int   ti = bi[k]; bi[k] = bi[k - 1]; bi[k - 1] = ti;
                }
            }
        }
    }

    // ---- stage 1: per-wave merge -> wave top-8 (8 rounds of u64 min) ----
    __shared__ unsigned long long warp_top[4][8];
    #pragma unroll 1
    for (int r = 0; r < 8; ++r) {
        unsigned long long mykey = pack_key(bd[0], bi[0]);
        unsigned long long wkey  = mykey;
        #pragma unroll
        for (int off = 32; off > 0; off >>= 1) {
            unsigned long long o = __shfl_xor(wkey, off, 64);
            wkey = (o < wkey) ? o : wkey;
        }
        if (mykey == wkey) {                   // unique winner: pop my head
            #pragma unroll
            for (int k = 0; k < 7; ++k) { bd[k] = bd[k + 1]; bi[k] = bi[k + 1]; }
            bd[7] = 3.4e38f; bi[7] = -1;
        }
        if (lane == 0) warp_top[wave][r] = wkey;
    }
    __syncthreads();

    // ---- stage 2: wave 0 merges 4x8 = 32 entries -> global top-8 ----
    __shared__ int nb_idx[K_NB];
    if (wave == 0) {
        unsigned long long key = (lane < 32)
            ? warp_top[lane >> 3][lane & 7]
            : 0xFFFFFFFFFFFFFFFFull;
        #pragma unroll 1
        for (int r = 0; r < K_NB; ++r) {
            unsigned long long wkey = key;
            #pragma unroll
            for (int off = 32; off > 0; off >>= 1) {
                unsigned long long o = __shfl_xor(wkey, off, 64);
                wkey = (o < wkey) ? o : wkey;
            }
            if (key == wkey) key = 0xFFFFFFFFFFFFFFFFull;   // invalidate winner
            if (lane == 0) nb_idx[r] = (int)(wkey & 0xFFFFFFFFu);
        }
    }
    __syncthreads();

    // ---- cosine phase: 2 neighbors per wave ----
    const float4* fi = reinterpret_cast<const float4*>(feat + (size_t)i * D_FEAT);
    const float4 vi  = fi[lane];
    const float  ri  = rnorm[i];
    float acc = 0.0f;
    #pragma unroll
    for (int t = 0; t < 2; ++t) {
        const int j = nb_idx[wave * 2 + t];
        const float4* fj = reinterpret_cast<const float4*>(feat + (size_t)j * D_FEAT);
        const float4 vj  = fj[lane];
        float s = vi.x * vj.x + vi.y * vj.y + vi.z * vj.z + vi.w * vj.w;
        #pragma unroll
        for (int off = 32; off > 0; off >>= 1) s += __shfl_xor(s, off, 64);
        if (lane == 0) acc += 1.0f - s * ri * rnorm[j];
    }

    __shared__ float wacc[4];
    if (lane == 0) wacc[wave] = acc;
    __syncthreads();
    if (tid == 0) partial[i] = wacc[0] + wacc[1] + wacc[2] + wacc[3];
}

// ---------------- Kernel C: deterministic final reduction -------------------
__global__ __launch_bounds__(256) void reduce_kernel(const float* __restrict__ partial,
                                                     float* __restrict__ out) {
    const int tid  = threadIdx.x;
    const int lane = tid & 63;
    const int wave = tid >> 6;
    float s = 0.0f;
    for (int j = tid; j < N_POINTS; j += 256) s += partial[j];
    #pragma unroll
    for (int off = 32; off > 0; off >>= 1) s += __shfl_xor(s, off, 64);
    __shared__ float sm[4];
    if (lane == 0) sm[wave] = s;
    __syncthreads();
    if (tid == 0)
        out[0] = 0.02f * (sm[0] + sm[1] + sm[2] + sm[3]) / (float)(N_POINTS * K_NB);
}

// ---------------- launch ----------------------------------------------------
extern "C" void kernel_launch(void* const* d_in, const int* in_sizes, int n_in,
                              void* d_out, int out_size, void* d_ws, size_t ws_size,
                              hipStream_t stream) {
    const float* feat   = (const float*)d_in[0];   // (16384, 256) f32
    const float* coords = (const float*)d_in[1];   // (16384, 3)  f32
    float* out     = (float*)d_out;                // scalar f32
    float* rnorm   = (float*)d_ws;                 // 16384 f32
    float* partial = rnorm + N_POINTS;             // 16384 f32

    norms_kernel<<<N_POINTS / 4, 256, 0, stream>>>(feat, rnorm);
    knn_cos_kernel<<<N_POINTS, 256, 0, stream>>>(coords, feat, rnorm, partial);
    reduce_kernel<<<1, 256, 0, stream>>>(partial, out);
}

// Round 2
// 259.672 us; speedup vs baseline: 1.3510x; 1.3510x over previous
//
#include <hip/hip_runtime.h>

#define N_POINTS 16384
#define D_FEAT   256
#define K_NB     8
#define QB       64                    // queries per block (one per lane)
#define WAVES    8                     // waves per block
#define CAND     (N_POINTS / WAVES)    // 2048 candidates per wave

// ---------- Kernel A: rnorm + pack coords into float4 (for s_load_dwordx4) --
__global__ __launch_bounds__(256) void prep_kernel(const float* __restrict__ feat,
                                                   const float* __restrict__ coords,
                                                   float* __restrict__ rnorm,
                                                   float4* __restrict__ coords4) {
    const int wave = threadIdx.x >> 6;
    const int lane = threadIdx.x & 63;
    const int row  = blockIdx.x * 4 + wave;
    const float4* f4 = reinterpret_cast<const float4*>(feat + (size_t)row * D_FEAT);
    float4 v = f4[lane];
    float s = v.x * v.x + v.y * v.y + v.z * v.z + v.w * v.w;
    #pragma unroll
    for (int off = 32; off > 0; off >>= 1) s += __shfl_xor(s, off, 64);
    if (lane == 0) {
        rnorm[row] = 1.0f / fmaxf(sqrtf(s), 1e-12f);
        coords4[row] = make_float4(coords[3 * row], coords[3 * row + 1],
                                   coords[3 * row + 2], 0.0f);
    }
}

// sorted top-8 insert, fully static indexing
#define INSERT(d2v, jv)                                                    \
    if ((d2v) < bd[7]) {                                                   \
        bd[7] = (d2v); bi[7] = (jv);                                       \
        _Pragma("unroll")                                                  \
        for (int _k = 7; _k > 0; --_k) {                                   \
            if (bd[_k] < bd[_k - 1]) {                                     \
                float _td = bd[_k]; bd[_k] = bd[_k - 1]; bd[_k - 1] = _td; \
                int   _ti = bi[_k]; bi[_k] = bi[_k - 1]; bi[_k - 1] = _ti; \
            }                                                              \
        }                                                                  \
    }

#define PROC(c, jv)                                                        \
    {                                                                      \
        float _dx = (c).x - xi, _dy = (c).y - yi, _dz = (c).z - zi;        \
        float _d2 = fmaf(_dx, _dx, fmaf(_dy, _dy, _dz * _dz));             \
        INSERT(_d2, (jv));                                                 \
    }

// ---------- Kernel B: 8-NN (wave-split scan) + cosine, one block = 64 queries
__global__ __launch_bounds__(512) void knn_cos_kernel(const float4* __restrict__ coords4,
                                                      const float* __restrict__ feat,
                                                      const float* __restrict__ rnorm,
                                                      float* __restrict__ partial) {
    const int tid  = threadIdx.x;
    const int lane = tid & 63;
    const int wave = tid >> 6;
    const int qg   = blockIdx.x * QB + lane;    // this lane's query point

    const float4 qc = coords4[qg];
    const float xi = qc.x, yi = qc.y, zi = qc.z;

    float bd[8];
    int   bi[8];
    #pragma unroll
    for (int k = 0; k < 8; ++k) { bd[k] = 3.4e38f; bi[k] = -1; }

    // wave-uniform candidate base -> scalar loads
    const int wbase = __builtin_amdgcn_readfirstlane(wave * CAND);

    // double-buffered uniform float4 loads, 4 candidates per iteration
    float4 b0 = coords4[wbase + 0];
    float4 b1 = coords4[wbase + 1];
    float4 b2 = coords4[wbase + 2];
    float4 b3 = coords4[wbase + 3];
    #pragma unroll 1
    for (int t = 0; t < CAND - 4; t += 4) {
        float4 n0 = coords4[wbase + t + 4];
        float4 n1 = coords4[wbase + t + 5];
        float4 n2 = coords4[wbase + t + 6];
        float4 n3 = coords4[wbase + t + 7];
        PROC(b0, wbase + t + 0);
        PROC(b1, wbase + t + 1);
        PROC(b2, wbase + t + 2);
        PROC(b3, wbase + t + 3);
        b0 = n0; b1 = n1; b2 = n2; b3 = n3;
    }
    PROC(b0, wbase + CAND - 4);
    PROC(b1, wbase + CAND - 3);
    PROC(b2, wbase + CAND - 2);
    PROC(b3, wbase + CAND - 1);

    // ---- write per-wave lists; merge 8x8 per query in LDS ----
    __shared__ float2 lists[WAVES][QB][K_NB];   // 32 KB
    __shared__ int    nbs[QB][K_NB];            // 2 KB
    #pragma unroll
    for (int k = 0; k < 8; ++k)
        lists[wave][lane][k] = make_float2(bd[k], __int_as_float(bi[k]));
    __syncthreads();

    if (tid < QB) {
        float md[8]; int mi[8];
        #pragma unroll
        for (int k = 0; k < 8; ++k) { md[k] = 3.4e38f; mi[k] = -1; }
        #pragma unroll 1
        for (int w = 0; w < WAVES; ++w) {
            #pragma unroll
            for (int k = 0; k < K_NB; ++k) {
                float2 e = lists[w][tid][k];
                int j = __float_as_int(e.y);
                if (j == qg || j < 0) continue;     // drop self / empty
                float d = e.x;
                if (d < md[7]) {
                    md[7] = d; mi[7] = j;
                    #pragma unroll
                    for (int _k = 7; _k > 0; --_k) {
                        if (md[_k] < md[_k - 1]) {
                            float td = md[_k]; md[_k] = md[_k - 1]; md[_k - 1] = td;
                            int   ti = mi[_k]; mi[_k] = mi[_k - 1]; mi[_k - 1] = ti;
                        }
                    }
                }
            }
        }
        #pragma unroll
        for (int k = 0; k < 8; ++k) nbs[tid][k] = mi[k];
    }
    __syncthreads();

    // ---- cosine phase: 512 threads = 512 (query, neighbor) pairs ----
    const int q    = tid >> 3;                  // 0..63
    const int kk   = tid & 7;                   // 0..7
    const int qrow = blockIdx.x * QB + q;
    const int jn   = nbs[q][kk];
    const float4* fq = reinterpret_cast<const float4*>(feat + (size_t)qrow * D_FEAT);
    const float4* fn = reinterpret_cast<const float4*>(feat + (size_t)jn * D_FEAT);
    float s = 0.0f;
    #pragma unroll 8
    for (int c = 0; c < D_FEAT / 4; ++c) {
        float4 a = fq[c];
        float4 b = fn[c];
        s = fmaf(a.x, b.x, fmaf(a.y, b.y, fmaf(a.z, b.z, fmaf(a.w, b.w, s))));
    }
    float val = 1.0f - s * rnorm[qrow] * rnorm[jn];

    // block reduction of 512 vals
    #pragma unroll
    for (int off = 32; off > 0; off >>= 1) val += __shfl_xor(val, off, 64);
    __shared__ float wacc[WAVES];
    if (lane == 0) wacc[wave] = val;
    __syncthreads();
    if (tid == 0) {
        float t = 0.0f;
        #pragma unroll
        for (int w = 0; w < WAVES; ++w) t += wacc[w];
        partial[blockIdx.x] = t;
    }
}

// ---------- Kernel C: deterministic final reduction -------------------------
__global__ __launch_bounds__(256) void reduce_kernel(const float* __restrict__ partial,
                                                     float* __restrict__ out) {
    const int tid  = threadIdx.x;
    const int lane = tid & 63;
    const int wave = tid >> 6;
    float s = partial[tid];                     // exactly 256 partials
    #pragma unroll
    for (int off = 32; off > 0; off >>= 1) s += __shfl_xor(s, off, 64);
    __shared__ float sm[4];
    if (lane == 0) sm[wave] = s;
    __syncthreads();
    if (tid == 0)
        out[0] = 0.02f * (sm[0] + sm[1] + sm[2] + sm[3]) / (float)(N_POINTS * K_NB);
}

// ---------- launch -----------------------------------------------------------
extern "C" void kernel_launch(void* const* d_in, const int* in_sizes, int n_in,
                              void* d_out, int out_size, void* d_ws, size_t ws_size,
                              hipStream_t stream) {
    const float* feat   = (const float*)d_in[0];   // (16384, 256) f32
    const float* coords = (const float*)d_in[1];   // (16384, 3)  f32
    float*  out     = (float*)d_out;
    float4* coords4 = (float4*)d_ws;                         // 256 KB
    float*  rnorm   = (float*)((char*)d_ws + N_POINTS * 16); // 64 KB
    float*  partial = rnorm + N_POINTS;                      // 1 KB

    prep_kernel<<<N_POINTS / 4, 256, 0, stream>>>(feat, coords, rnorm, coords4);
    knn_cos_kernel<<<N_POINTS / QB, 512, 0, stream>>>(coords4, feat, rnorm, partial);
    reduce_kernel<<<1, 256, 0, stream>>>(partial, out);
}

// Round 3
// 58.656 us; speedup vs baseline: 5.9809x; 4.4270x over previous
//
#include <hip/hip_runtime.h>

#define N_POINTS 16384
#define D_FEAT   256
#define K_NB     8
#define G        12
#define NCELL    (G * G * G)

__device__ __forceinline__ int cell_of(float x, float y, float z) {
    int cx = min(max((int)(x * (float)G), 0), G - 1);
    int cy = min(max((int)(y * (float)G), 0), G - 1);
    int cz = min(max((int)(z * (float)G), 0), G - 1);
    return (cz * G + cy) * G + cx;
}

// ---------- rnorm[i] = 1 / max(||feat[i]||, 1e-12) --------------------------
__global__ __launch_bounds__(256) void prep_kernel(const float* __restrict__ feat,
                                                   float* __restrict__ rnorm) {
    const int wave = threadIdx.x >> 6;
    const int lane = threadIdx.x & 63;
    const int row  = blockIdx.x * 4 + wave;
    const float4* f4 = reinterpret_cast<const float4*>(feat + (size_t)row * D_FEAT);
    float4 v = f4[lane];
    float s = v.x * v.x + v.y * v.y + v.z * v.z + v.w * v.w;
    #pragma unroll
    for (int off = 32; off > 0; off >>= 1) s += __shfl_xor(s, off, 64);
    if (lane == 0) rnorm[row] = 1.0f / fmaxf(sqrtf(s), 1e-12f);
}

// ---------- histogram -------------------------------------------------------
__global__ __launch_bounds__(256) void hist_kernel(const float* __restrict__ coords,
                                                   int* __restrict__ count) {
    const int i = blockIdx.x * 256 + threadIdx.x;
    const int c = cell_of(coords[3 * i], coords[3 * i + 1], coords[3 * i + 2]);
    atomicAdd(&count[c], 1);
}

// ---------- exclusive prefix scan over NCELL (+ total at [NCELL]) -----------
__global__ __launch_bounds__(256) void scan_kernel(const int* __restrict__ count,
                                                   int* __restrict__ cell_start) {
    const int t = threadIdx.x, lane = t & 63, wave = t >> 6;
    const int base = t * 7;                       // 256*7 = 1792 >= NCELL+1
    int c[7];
    int tot = 0;
    #pragma unroll
    for (int k = 0; k < 7; ++k) {
        c[k] = (base + k < NCELL) ? count[base + k] : 0;
        tot += c[k];
    }
    int v = tot;                                  // inclusive scan across 256 threads
    #pragma unroll
    for (int off = 1; off < 64; off <<= 1) {
        int o = __shfl_up(v, off, 64);
        if (lane >= off) v += o;
    }
    __shared__ int wtot[4];
    if (lane == 63) wtot[wave] = v;
    __syncthreads();
    int woff = 0;
    for (int w = 0; w < wave; ++w) woff += wtot[w];
    int ex = woff + v - tot;                      // exclusive start of this chunk
    #pragma unroll
    for (int k = 0; k < 7; ++k) {
        int idx = base + k;
        if (idx <= NCELL) cell_start[idx] = ex;
        ex += c[k];
    }
}

// ---------- scatter: sorted[] = (x,y,z, orig_idx bits) ----------------------
__global__ __launch_bounds__(256) void scatter_kernel(const float* __restrict__ coords,
                                                      const int* __restrict__ cell_start,
                                                      int* __restrict__ cursor,
                                                      float4* __restrict__ sorted) {
    const int i = blockIdx.x * 256 + threadIdx.x;
    const float x = coords[3 * i], y = coords[3 * i + 1], z = coords[3 * i + 2];
    const int c = cell_of(x, y, z);
    const int slot = atomicAdd(&cursor[c], 1);
    sorted[cell_start[c] + slot] = make_float4(x, y, z, __int_as_float(i));
}

// sorted top-8 insert, fully static indexing
#define INSERT(d2v, jv)                                                    \
    if ((d2v) < bd[7]) {                                                   \
        bd[7] = (d2v); bi[7] = (jv);                                       \
        _Pragma("unroll")                                                  \
        for (int _k = 7; _k > 0; --_k) {                                   \
            if (bd[_k] < bd[_k - 1]) {                                     \
                float _td = bd[_k]; bd[_k] = bd[_k - 1]; bd[_k - 1] = _td; \
                int   _ti = bi[_k]; bi[_k] = bi[_k - 1]; bi[_k - 1] = _ti; \
            }                                                              \
        }                                                                  \
    }

// ---------- kNN (grid) + cosine: one wave per query -------------------------
__global__ __launch_bounds__(256) void knn_cos_kernel(const float4* __restrict__ sorted,
                                                      const int* __restrict__ cell_start,
                                                      const float* __restrict__ feat,
                                                      const float* __restrict__ rnorm,
                                                      float* __restrict__ partial) {
    const int tid  = threadIdx.x;
    const int lane = tid & 63;
    const int wave = tid >> 6;
    const int q    = blockIdx.x * 4 + wave;       // sorted position

    const float4 qp = sorted[q];
    const float xi = qp.x, yi = qp.y, zi = qp.z;
    const int qorig = __float_as_int(qp.w);
    const int cx = min(max((int)(xi * (float)G), 0), G - 1);
    const int cy = min(max((int)(yi * (float)G), 0), G - 1);
    const int cz = min(max((int)(zi * (float)G), 0), G - 1);

    float bd[8];
    int   bi[8];
    #pragma unroll
    for (int k = 0; k < 8; ++k) { bd[k] = 3.4e38f; bi[k] = -1; }

    // 9 contiguous x-row segments (3 z x 3 y), each spanning up to 3 x-cells
    #pragma unroll 1
    for (int dz = -1; dz <= 1; ++dz) {
        const int z = cz + dz;
        if (z < 0 || z >= G) continue;
        #pragma unroll 1
        for (int dy = -1; dy <= 1; ++dy) {
            const int y = cy + dy;
            if (y < 0 || y >= G) continue;
            const int rowb = (z * G + y) * G;
            const int x0 = max(cx - 1, 0), x1 = min(cx + 1, G - 1);
            const int s = __builtin_amdgcn_readfirstlane(cell_start[rowb + x0]);
            const int e = __builtin_amdgcn_readfirstlane(cell_start[rowb + x1 + 1]);
            for (int b = s; b < e; b += 64) {
                const int idx = b + lane;
                if (idx < e) {
                    const float4 p = sorted[idx];
                    const float dx = p.x - xi, dy2 = p.y - yi, dz2 = p.z - zi;
                    const float d2 = fmaf(dx, dx, fmaf(dy2, dy2, dz2 * dz2));
                    const int j = __float_as_int(p.w);
                    if (j != qorig) INSERT(d2, j);
                }
            }
        }
    }

    // ---- wave merge: 8 rounds of u64 min over (d2 bits << 32 | idx) ----
    int nb[8];
    #pragma unroll
    for (int r = 0; r < K_NB; ++r) {
        unsigned long long my =
            ((unsigned long long)__float_as_uint(bd[0]) << 32) | (unsigned int)bi[0];
        unsigned long long w = my;
        #pragma unroll
        for (int off = 32; off > 0; off >>= 1) {
            unsigned long long o = __shfl_xor(w, off, 64);
            w = (o < w) ? o : w;
        }
        if (my == w) {                            // unique winner pops its head
            #pragma unroll
            for (int k = 0; k < 7; ++k) { bd[k] = bd[k + 1]; bi[k] = bi[k + 1]; }
            bd[7] = 3.4e38f; bi[7] = -1;
        }
        nb[r] = (int)(w & 0xFFFFFFFFu);
    }

    // ---- cosine: 8 neighbors, per-lane partial accumulate, one reduce ----
    const float4* fq = reinterpret_cast<const float4*>(feat + (size_t)qorig * D_FEAT);
    const float4 a = fq[lane];
    const float rq = rnorm[qorig];
    float racc = 0.0f;
    #pragma unroll
    for (int r = 0; r < K_NB; ++r) {
        int j = nb[r];
        if (j < 0) j = qorig;                     // safety (never expected)
        const float4* fn = reinterpret_cast<const float4*>(feat + (size_t)j * D_FEAT);
        const float4 b = fn[lane];
        const float s = fmaf(a.x, b.x, fmaf(a.y, b.y, fmaf(a.z, b.z, a.w * b.w)));
        racc = fmaf(s, rq * rnorm[j], racc);
    }
    #pragma unroll
    for (int off = 32; off > 0; off >>= 1) racc += __shfl_xor(racc, off, 64);
    const float wval = (float)K_NB - racc;        // sum of (1 - cos)

    __shared__ float wacc[4];
    if (lane == 0) wacc[wave] = wval;
    __syncthreads();
    if (tid == 0)
        partial[blockIdx.x] = wacc[0] + wacc[1] + wacc[2] + wacc[3];
}

// ---------- final reduction (4096 partials, fixed order) --------------------
__global__ __launch_bounds__(256) void reduce_kernel(const float* __restrict__ partial,
                                                     float* __restrict__ out) {
    const int tid  = threadIdx.x;
    const int lane = tid & 63;
    const int wave = tid >> 6;
    float s = 0.0f;
    for (int j = tid; j < N_POINTS / 4; j += 256) s += partial[j];
    #pragma unroll
    for (int off = 32; off > 0; off >>= 1) s += __shfl_xor(s, off, 64);
    __shared__ float sm[4];
    if (lane == 0) sm[wave] = s;
    __syncthreads();
    if (tid == 0)
        out[0] = 0.02f * (sm[0] + sm[1] + sm[2] + sm[3]) / (float)(N_POINTS * K_NB);
}

// ---------- launch ----------------------------------------------------------
extern "C" void kernel_launch(void* const* d_in, const int* in_sizes, int n_in,
                              void* d_out, int out_size, void* d_ws, size_t ws_size,
                              hipStream_t stream) {
    const float* feat   = (const float*)d_in[0];   // (16384, 256) f32
    const float* coords = (const float*)d_in[1];   // (16384, 3)  f32
    float* out = (float*)d_out;

    char* ws = (char*)d_ws;
    float4* sorted     = (float4*)ws;                          // 262144 B
    float*  rnorm      = (float*)(ws + 262144);                //  65536 B
    float*  partial    = (float*)(ws + 262144 + 65536);        //  16384 B
    int*    counts     = (int*)(ws + 262144 + 65536 + 16384);  // NCELL
    int*    cursor     = counts + NCELL;                       // NCELL
    int*    cell_start = cursor + NCELL;                       // NCELL + 1

    hipMemsetAsync(counts, 0, 2 * NCELL * sizeof(int), stream);
    prep_kernel<<<N_POINTS / 4, 256, 0, stream>>>(feat, rnorm);
    hist_kernel<<<N_POINTS / 256, 256, 0, stream>>>(coords, counts);
    scan_kernel<<<1, 256, 0, stream>>>(counts, cell_start);
    scatter_kernel<<<N_POINTS / 256, 256, 0, stream>>>(coords, cell_start, cursor, sorted);
    knn_cos_kernel<<<N_POINTS / 4, 256, 0, stream>>>(sorted, cell_start, feat, rnorm, partial);
    reduce_kernel<<<1, 256, 0, stream>>>(partial, out);
}

// Round 4
// 54.273 us; speedup vs baseline: 6.4640x; 1.0808x over previous
//
#include <hip/hip_runtime.h>

#define N_POINTS 16384
#define D_FEAT   256
#define K_NB     8
#define G        12
#define NCELL    (G * G * G)

__device__ __forceinline__ int cell_of(float x, float y, float z) {
    int cx = min(max((int)(x * (float)G), 0), G - 1);
    int cy = min(max((int)(y * (float)G), 0), G - 1);
    int cz = min(max((int)(z * (float)G), 0), G - 1);
    return (cz * G + cy) * G + cx;
}

// ---------- rnorm[i] = 1/max(||feat[i]||,1e-12); block 0 also zeroes counts -
__global__ __launch_bounds__(256) void prep_kernel(const float* __restrict__ feat,
                                                   float* __restrict__ rnorm,
                                                   int* __restrict__ counts) {
    if (blockIdx.x == 0) {
        for (int c = threadIdx.x; c < NCELL; c += 256) counts[c] = 0;
    }
    const int wave = threadIdx.x >> 6;
    const int lane = threadIdx.x & 63;
    const int row  = blockIdx.x * 4 + wave;
    const float4* f4 = reinterpret_cast<const float4*>(feat + (size_t)row * D_FEAT);
    float4 v = f4[lane];
    float s = v.x * v.x + v.y * v.y + v.z * v.z + v.w * v.w;
    #pragma unroll
    for (int off = 32; off > 0; off >>= 1) s += __shfl_xor(s, off, 64);
    if (lane == 0) rnorm[row] = 1.0f / fmaxf(sqrtf(s), 1e-12f);
}

// ---------- histogram -------------------------------------------------------
__global__ __launch_bounds__(256) void hist_kernel(const float* __restrict__ coords,
                                                   int* __restrict__ count) {
    const int i = blockIdx.x * 256 + threadIdx.x;
    const int c = cell_of(coords[3 * i], coords[3 * i + 1], coords[3 * i + 2]);
    atomicAdd(&count[c], 1);
}

// ---------- exclusive prefix scan -> cell_start AND cursor ------------------
__global__ __launch_bounds__(256) void scan_kernel(const int* __restrict__ count,
                                                   int* __restrict__ cell_start,
                                                   int* __restrict__ cursor) {
    const int t = threadIdx.x, lane = t & 63, wave = t >> 6;
    const int base = t * 7;                       // 256*7 = 1792 >= NCELL+1
    int c[7];
    int tot = 0;
    #pragma unroll
    for (int k = 0; k < 7; ++k) {
        c[k] = (base + k < NCELL) ? count[base + k] : 0;
        tot += c[k];
    }
    int v = tot;                                  // inclusive scan across 256 threads
    #pragma unroll
    for (int off = 1; off < 64; off <<= 1) {
        int o = __shfl_up(v, off, 64);
        if (lane >= off) v += o;
    }
    __shared__ int wtot[4];
    if (lane == 63) wtot[wave] = v;
    __syncthreads();
    int woff = 0;
    for (int w = 0; w < wave; ++w) woff += wtot[w];
    int ex = woff + v - tot;                      // exclusive start of this chunk
    #pragma unroll
    for (int k = 0; k < 7; ++k) {
        int idx = base + k;
        if (idx <= NCELL) cell_start[idx] = ex;
        if (idx < NCELL)  cursor[idx] = ex;
        ex += c[k];
    }
}

// ---------- scatter: sorted[slot] = (x,y,z, orig_idx bits) ------------------
__global__ __launch_bounds__(256) void scatter_kernel(const float* __restrict__ coords,
                                                      int* __restrict__ cursor,
                                                      float4* __restrict__ sorted) {
    const int i = blockIdx.x * 256 + threadIdx.x;
    const float x = coords[3 * i], y = coords[3 * i + 1], z = coords[3 * i + 2];
    const int c = cell_of(x, y, z);
    const int slot = atomicAdd(&cursor[c], 1);    // absolute position
    sorted[slot] = make_float4(x, y, z, __int_as_float(i));
}

// sorted top-8 insert, fully static indexing
#define INSERT(d2v, jv)                                                    \
    if ((d2v) < bd[7]) {                                                   \
        bd[7] = (d2v); bi[7] = (jv);                                       \
        _Pragma("unroll")                                                  \
        for (int _k = 7; _k > 0; --_k) {                                   \
            if (bd[_k] < bd[_k - 1]) {                                     \
                float _td = bd[_k]; bd[_k] = bd[_k - 1]; bd[_k - 1] = _td; \
                int   _ti = bi[_k]; bi[_k] = bi[_k - 1]; bi[_k - 1] = _ti; \
            }                                                              \
        }                                                                  \
    }

// ---------- kNN (grid) + cosine: one wave per query -------------------------
__global__ __launch_bounds__(256) void knn_cos_kernel(const float4* __restrict__ sorted,
                                                      const int* __restrict__ cell_start,
                                                      const float* __restrict__ feat,
                                                      const float* __restrict__ rnorm,
                                                      float* __restrict__ partial) {
    const int tid  = threadIdx.x;
    const int lane = tid & 63;
    const int wave = tid >> 6;
    const int q    = blockIdx.x * 4 + wave;       // sorted position

    const float4 qp = sorted[q];
    const float xi = qp.x, yi = qp.y, zi = qp.z;
    const int qorig = __float_as_int(qp.w);
    const int cx = min(max((int)(xi * (float)G), 0), G - 1);
    const int cy = min(max((int)(yi * (float)G), 0), G - 1);
    const int cz = min(max((int)(zi * (float)G), 0), G - 1);

    float bd[8];
    int   bi[8];
    #pragma unroll
    for (int k = 0; k < 8; ++k) { bd[k] = 3.4e38f; bi[k] = -1; }

    // 9 contiguous x-row segments (3 z x 3 y), each spanning up to 3 x-cells
    #pragma unroll 1
    for (int dz = -1; dz <= 1; ++dz) {
        const int z = cz + dz;
        if (z < 0 || z >= G) continue;
        #pragma unroll 1
        for (int dy = -1; dy <= 1; ++dy) {
            const int y = cy + dy;
            if (y < 0 || y >= G) continue;
            const int rowb = (z * G + y) * G;
            const int x0 = max(cx - 1, 0), x1 = min(cx + 1, G - 1);
            const int s = __builtin_amdgcn_readfirstlane(cell_start[rowb + x0]);
            const int e = __builtin_amdgcn_readfirstlane(cell_start[rowb + x1 + 1]);
            for (int b = s; b < e; b += 64) {
                const int idx = b + lane;
                if (idx < e) {
                    const float4 p = sorted[idx];
                    const float dx = p.x - xi, dy2 = p.y - yi, dz2 = p.z - zi;
                    const float d2 = fmaf(dx, dx, fmaf(dy2, dy2, dz2 * dz2));
                    const int j = __float_as_int(p.w);
                    if (j != qorig) INSERT(d2, j);
                }
            }
        }
    }

    // ---- wave merge: 8 rounds of u64 min over (d2 bits << 32 | idx) ----
    int nb[8];
    #pragma unroll
    for (int r = 0; r < K_NB; ++r) {
        unsigned long long my =
            ((unsigned long long)__float_as_uint(bd[0]) << 32) | (unsigned int)bi[0];
        unsigned long long w = my;
        #pragma unroll
        for (int off = 32; off > 0; off >>= 1) {
            unsigned long long o = __shfl_xor(w, off, 64);
            w = (o < w) ? o : w;
        }
        if (my == w) {                            // unique winner pops its head
            #pragma unroll
            for (int k = 0; k < 7; ++k) { bd[k] = bd[k + 1]; bi[k] = bi[k + 1]; }
            bd[7] = 3.4e38f; bi[7] = -1;
        }
        nb[r] = (int)(w & 0xFFFFFFFFu);
    }

    // ---- cosine: 8 neighbors, per-lane partial accumulate, one reduce ----
    const float4* fq = reinterpret_cast<const float4*>(feat + (size_t)qorig * D_FEAT);
    const float4 a = fq[lane];
    const float rq = rnorm[qorig];
    float racc = 0.0f;
    #pragma unroll
    for (int r = 0; r < K_NB; ++r) {
        int j = nb[r];
        if (j < 0) j = qorig;                     // safety (never expected)
        const float4* fn = reinterpret_cast<const float4*>(feat + (size_t)j * D_FEAT);
        const float4 b = fn[lane];
        const float s = fmaf(a.x, b.x, fmaf(a.y, b.y, fmaf(a.z, b.z, a.w * b.w)));
        racc = fmaf(s, rq * rnorm[j], racc);
    }
    #pragma unroll
    for (int off = 32; off > 0; off >>= 1) racc += __shfl_xor(racc, off, 64);
    const float wval = (float)K_NB - racc;        // sum of (1 - cos)

    __shared__ float wacc[4];
    if (lane == 0) wacc[wave] = wval;
    __syncthreads();
    if (tid == 0)
        partial[blockIdx.x] = wacc[0] + wacc[1] + wacc[2] + wacc[3];
}

// ---------- final reduction (4096 partials, fixed order) --------------------
__global__ __launch_bounds__(256) void reduce_kernel(const float* __restrict__ partial,
                                                     float* __restrict__ out) {
    const int tid  = threadIdx.x;
    const int lane = tid & 63;
    const int wave = tid >> 6;
    float s = 0.0f;
    for (int j = tid; j < N_POINTS / 4; j += 256) s += partial[j];
    #pragma unroll
    for (int off = 32; off > 0; off >>= 1) s += __shfl_xor(s, off, 64);
    __shared__ float sm[4];
    if (lane == 0) sm[wave] = s;
    __syncthreads();
    if (tid == 0)
        out[0] = 0.02f * (sm[0] + sm[1] + sm[2] + sm[3]) / (float)(N_POINTS * K_NB);
}

// ---------- launch ----------------------------------------------------------
extern "C" void kernel_launch(void* const* d_in, const int* in_sizes, int n_in,
                              void* d_out, int out_size, void* d_ws, size_t ws_size,
                              hipStream_t stream) {
    const float* feat   = (const float*)d_in[0];   // (16384, 256) f32
    const float* coords = (const float*)d_in[1];   // (16384, 3)  f32
    float* out = (float*)d_out;

    char* ws = (char*)d_ws;
    float4* sorted     = (float4*)ws;                          // 262144 B
    float*  rnorm      = (float*)(ws + 262144);                //  65536 B
    float*  partial    = (float*)(ws + 262144 + 65536);        //  16384 B
    int*    counts     = (int*)(ws + 262144 + 65536 + 16384);  // NCELL
    int*    cursor     = counts + NCELL;                       // NCELL
    int*    cell_start = cursor + NCELL;                       // NCELL + 1

    prep_kernel<<<N_POINTS / 4, 256, 0, stream>>>(feat, rnorm, counts);
    hist_kernel<<<N_POINTS / 256, 256, 0, stream>>>(coords, counts);
    scan_kernel<<<1, 256, 0, stream>>>(counts, cell_start, cursor);
    scatter_kernel<<<N_POINTS / 256, 256, 0, stream>>>(coords, cursor, sorted);
    knn_cos_kernel<<<N_POINTS / 4, 256, 0, stream>>>(sorted, cell_start, feat, rnorm, partial);
    reduce_kernel<<<1, 256, 0, stream>>>(partial, out);
}